// Round 10
// baseline (235.997 us; speedup 1.0000x reference)
//
#include <hip/hip_runtime.h>

#define B_ 4
#define T_ 4096
#define C_ 1024
#define H_ 64

typedef _Float16 half8  __attribute__((ext_vector_type(8)));
typedef _Float16 half4_ __attribute__((ext_vector_type(4)));
typedef float    floatx4 __attribute__((ext_vector_type(4)));

#define MFMA16(a, b, c)  __builtin_amdgcn_mfma_f32_16x16x32_f16(a, b, c, 0, 0, 0)
#define MFMA16K(a, b, c) __builtin_amdgcn_mfma_f32_16x16x16f16(a, b, c, 0, 0, 0)
#define LO4(v) __builtin_shufflevector(v, v, 0, 1, 2, 3)
#define HI4(v) __builtin_shufflevector(v, v, 4, 5, 6, 7)

// ---------------------------------------------------------------------------
// Kernel 1: pack W into MFMA-fragment order + zero the 128 merge tickets.
// ---------------------------------------------------------------------------
__global__ __launch_bounds__(256) void pack_w_kn(
    const float* __restrict__ Wq, const float* __restrict__ Wk,
    const float* __restrict__ Wv, _Float16* __restrict__ Wt2,
    int* __restrict__ tick)
{
    if (blockIdx.x == 0 && threadIdx.x < 128) tick[threadIdx.x] = 0;
    const int idx  = blockIdx.x * 256 + threadIdx.x;  // 0 .. 196607
    const int mt   = idx >> 14;
    const int j    = (idx >> 10) & 15;
    const int f    = (idx >> 9) & 1;
    const int lane = (idx >> 3) & 63;
    const int jj   = idx & 7;
    const int q = lane >> 4, c = lane & 15;
    const int k  = j * 64 + f * 32 + q * 8 + jj;
    const int hp = mt * 16 + c;                       // 0..191
    const float* W = (hp < 64) ? Wq : (hp < 128) ? Wk : Wv;
    Wt2[idx] = (_Float16)W[k * H_ + (hp & 63)];
}

// ---------------------------------------------------------------------------
// Kernel 2: fused QKV projection (unchanged).  Vpk in 16x16x16 A-frag order.
// ---------------------------------------------------------------------------
__global__ __launch_bounds__(512) void qkv_kn(
    const float* __restrict__ x, const _Float16* __restrict__ Wt2,
    _Float16* __restrict__ Qh, _Float16* __restrict__ Kpk,
    _Float16* __restrict__ Vpk)
{
    __shared__ _Float16 xs[2][32][72];                // 9216 B
    const int tid  = threadIdx.x;
    const int lane = tid & 63, w = tid >> 6;
    const int q    = lane >> 4, c = lane & 15;
    const int nt   = w & 1;                           // n-half (16 rows)
    const int mg   = w >> 1;                          // m-group (3 m-tiles)
    const int row0 = blockIdx.x * 32;

    const int srow = tid >> 4, scol = (tid & 15) * 4;
    const float* xg = x + (size_t)(row0 + srow) * C_ + scol;

    floatx4 acc[3];
    #pragma unroll
    for (int i = 0; i < 3; ++i) acc[i] = floatx4{0.f, 0.f, 0.f, 0.f};

    float4 g = *(const float4*)xg;                    // preload tile 0

    for (int j = 0; j < 16; ++j) {
        half4_ hv;
        hv[0] = (_Float16)g.x; hv[1] = (_Float16)g.y;
        hv[2] = (_Float16)g.z; hv[3] = (_Float16)g.w;
        *(half4_*)(&xs[j & 1][srow][scol]) = hv;
        __syncthreads();
        if (j < 15) g = *(const float4*)(xg + (j + 1) * 64);

        const _Float16* xrow = &xs[j & 1][nt * 16 + c][q * 8];
        const half8 b0 = *(const half8*)xrow;
        const half8 b1 = *(const half8*)(xrow + 32);

        half8 a[6];
        #pragma unroll
        for (int i = 0; i < 3; ++i) {
            const size_t fb = ((size_t)((mg * 3 + i) * 16 + j) * 2) * 512 + lane * 8;
            a[i * 2]     = *(const half8*)(Wt2 + fb);
            a[i * 2 + 1] = *(const half8*)(Wt2 + fb + 512);
        }
        #pragma unroll
        for (int i = 0; i < 3; ++i) {
            acc[i] = MFMA16(a[i * 2],     b0, acc[i]);
            acc[i] = MFMA16(a[i * 2 + 1], b1, acc[i]);
        }
    }

    const int row = row0 + nt * 16 + c;
    const int b = row >> 12, t4 = row & (T_ - 1);
    const int kt = t4 >> 6;
    const size_t tbase = ((size_t)b * 64 + kt) * 4096;
    const int mtk = (t4 >> 4) & 3;
    const int kk  = t4 & 63;

    #pragma unroll
    for (int i = 0; i < 3; ++i) {
        const int gi = mg * 3 + i;
        if (gi < 4) {                                 // Q row-major
            half4_ v;
            #pragma unroll
            for (int r = 0; r < 4; ++r) v[r] = (_Float16)acc[i][r];
            *(half4_*)(Qh + (size_t)row * H_ + gi * 16 + q * 4) = v;
        } else if (gi < 8) {                          // K fragment-packed (16x16x32 A-frag)
            half4_ v;
            #pragma unroll
            for (int r = 0; r < 4; ++r) v[r] = (_Float16)acc[i][r];
            const int e  = gi - 4;
            const int f  = e >> 1;
            const int qa = (e * 2 + (q >> 1)) & 3;
            *(half4_*)(Kpk + tbase + ((size_t)(mtk * 2 + f) * 64 + qa * 16 + c) * 8
                       + (q & 1) * 4) = v;
        } else {                                      // V 16x16x16 A-frag packed
            const int mtv = gi - 8;
            const int qa2 = (kk >> 2) & 3;
            const int h4  = (kk >> 4) & 1;
            const int f2  = kk >> 5;
            const int i2  = kk & 3;
            #pragma unroll
            for (int r = 0; r < 4; ++r) {
                const int cv = q * 4 + r;             // h & 15
                Vpk[tbase + ((size_t)(mtv * 2 + f2) * 64 + qa2 * 16 + cv) * 8
                    + h4 * 4 + i2] = (_Float16)acc[i][r];
            }
        }
    }
}

// ---------------------------------------------------------------------------
// Kernel 3: causal flash attention, LDS-shared K/V (r9 loop unchanged) with
// FUSED split-K combine: after writing its partial, each block releases
// (vmcnt-drained barrier -> __threadfence L2-writeback -> atomicAdd ticket);
// the 8th arrival acquires and merges all 8 partials for its 128-row q-tile,
// writing the final output directly.  Saves the combine kernel launch + gap
// and overlaps merges with the tail of other blocks' compute (r9 post-mortem:
// combine plumbing ate the traffic win).  Merge order fixed -> deterministic.
// ---------------------------------------------------------------------------
__global__ __launch_bounds__(512, 4) void attn_kn(
    const _Float16* __restrict__ Qh, const _Float16* __restrict__ Kpk,
    const _Float16* __restrict__ Vpk, float* __restrict__ Opart,
    float* __restrict__ Mp, float* __restrict__ Lp, int* __restrict__ tick,
    float* __restrict__ out)
{
    __shared__ __align__(16) char smem[36864];        // KVs overlay / merge sO
    __shared__ int s_last;
    _Float16 (*KVs)[2][4096] = (_Float16 (*)[2][4096])smem;
    const int tid  = threadIdx.x;
    const int lane = tid & 63;
    const int w    = tid >> 6;                        // 0..7
    const int q    = lane >> 4, c = lane & 15;

    // decode: batch per XCD pair; tau heavy-first; s = split-K slice
    const int bid  = blockIdx.x;
    const int xcd  = bid & 7;
    const int slot = bid >> 3;                        // 0..127
    const int b    = xcd >> 1;
    const int tau  = 31 - (slot >> 2);                // 0..31, heavy first
    const int s    = ((slot & 3) << 1) | (xcd & 1);   // 0..7
    const int row0 = tau * 128;
    const int wrow0 = row0 + w * 16;                  // this wave's first row
    const int nk_blk = 2 * tau + 2;                   // block stages kt<nk_blk
    const int nk_w   = (wrow0 >> 6) + 1;              // wave needs kt<nk_w
    const int ntb = (s < nk_blk) ? (((nk_blk - 1 - s) >> 3) + 1) : 0;

    // Q B-frag for this wave's 16 rows, pre-scaled by (1/8)*log2(e)
    const _Float16* qb = Qh + (size_t)(b * T_ + wrow0 + c) * H_;
    half8 bq0 = *(const half8*)(qb + q * 8);
    half8 bq1 = *(const half8*)(qb + 32 + q * 8);
    const _Float16 qs = (_Float16)0.18033688f;
    bq0 *= qs; bq1 *= qs;

    floatx4 o[4];
    #pragma unroll
    for (int i = 0; i < 4; ++i) o[i] = floatx4{0.f, 0.f, 0.f, 0.f};
    float m = -3.0e38f, l = 0.f;

    const _Float16* Kb = Kpk + (size_t)b * 262144;    // b * 64 * 4096
    const _Float16* Vb = Vpk + (size_t)b * 262144;

    if (ntb > 0) {                                    // stage first tile
        const _Float16* Kt = Kb + (size_t)s * 4096;
        const _Float16* Vt = Vb + (size_t)s * 4096;
        *(half8*)(&KVs[0][0][tid * 8]) = *(const half8*)(Kt + tid * 8);
        *(half8*)(&KVs[0][1][tid * 8]) = *(const half8*)(Vt + tid * 8);
    }
    __syncthreads();

    #pragma unroll 1
    for (int i = 0; i < ntb; ++i) {
        const int kt = s + 8 * i;
        const bool more = (i + 1 < ntb);
        half8 gk, gv;
        if (more) {                                   // issue next-tile loads
            const _Float16* Kt = Kb + (size_t)(kt + 8) * 4096;
            const _Float16* Vt = Vb + (size_t)(kt + 8) * 4096;
            gk = *(const half8*)(Kt + tid * 8);
            gv = *(const half8*)(Vt + tid * 8);
        }

        if (kt < nk_w) {                              // wave-uniform guard
            const _Float16* Ks = &KVs[i & 1][0][0];
            const _Float16* Vs = &KVs[i & 1][1][0];

            floatx4 sS[4];
            __builtin_amdgcn_s_setprio(1);
            #pragma unroll
            for (int mt = 0; mt < 4; ++mt) {
                const half8 ka = *(const half8*)(Ks + ((mt * 2)     * 64 + lane) * 8);
                const half8 kb2= *(const half8*)(Ks + ((mt * 2 + 1) * 64 + lane) * 8);
                floatx4 z = floatx4{0.f, 0.f, 0.f, 0.f};
                z = MFMA16(ka, bq0, z);
                sS[mt] = MFMA16(kb2, bq1, z);
            }
            __builtin_amdgcn_s_setprio(0);

            if (kt == nk_w - 1) {                     // causal mask (diag tile)
                const int kb0 = kt * 64;
                #pragma unroll
                for (int mt = 0; mt < 4; ++mt)
                    #pragma unroll
                    for (int r = 0; r < 4; ++r)
                        if (kb0 + mt * 16 + q * 4 + r > wrow0 + c)
                            sS[mt][r] = -3.0e38f;
            }

            // online softmax (lane holds 16 scores of ONE q-row); T13 defer
            float mx = sS[0][0];
            #pragma unroll
            for (int mt = 0; mt < 4; ++mt)
                #pragma unroll
                for (int r = 0; r < 4; ++r) mx = fmaxf(mx, sS[mt][r]);
            mx = fmaxf(mx, __shfl_xor(mx, 16, 64));
            mx = fmaxf(mx, __shfl_xor(mx, 32, 64));
            if (!__all(mx <= m + 8.f)) {
                const float mn    = fmaxf(m, mx);
                const float alpha = exp2f(m - mn);
                l *= alpha;
                #pragma unroll
                for (int mt = 0; mt < 4; ++mt) o[mt] *= alpha;
                m = mn;
            }
            half4_ ph[4];
            float sl = 0.f;
            #pragma unroll
            for (int mt = 0; mt < 4; ++mt)
                #pragma unroll
                for (int r = 0; r < 4; ++r) {
                    const float ev = exp2f(sS[mt][r] - m);
                    sl += ev;
                    ph[mt][r] = (_Float16)ev;
                }
            sl += __shfl_xor(sl, 16, 64);
            sl += __shfl_xor(sl, 32, 64);
            l += sl;

            __builtin_amdgcn_s_setprio(1);
            #pragma unroll
            for (int mt = 0; mt < 4; ++mt) {
                const half8 va = *(const half8*)(Vs + ((mt * 2)     * 64 + lane) * 8);
                const half8 vb = *(const half8*)(Vs + ((mt * 2 + 1) * 64 + lane) * 8);
                o[mt] = MFMA16K(LO4(va), ph[0], o[mt]);
                o[mt] = MFMA16K(HI4(va), ph[1], o[mt]);
                o[mt] = MFMA16K(LO4(vb), ph[2], o[mt]);
                o[mt] = MFMA16K(HI4(vb), ph[3], o[mt]);
            }
            __builtin_amdgcn_s_setprio(0);
        }

        __syncthreads();                              // all reads of buf done
        if (more) {                                   // block-uniform
            *(half8*)(&KVs[(i + 1) & 1][0][tid * 8]) = gk;
            *(half8*)(&KVs[(i + 1) & 1][1][tid * 8]) = gv;
            __syncthreads();
        }
    }

    // ---- write per-wave unnormalized partial (fragment-native, coalesced) -
    float* Ob = Opart + ((size_t)bid * 8 + w) * 1024;
    #pragma unroll
    for (int mt = 0; mt < 4; ++mt)
        *(floatx4*)(Ob + mt * 256 + lane * 4) = o[mt];
    if (q == 0) {
        Mp[(size_t)bid * 128 + w * 16 + c] = m;
        Lp[(size_t)bid * 128 + w * 16 + c] = l;
    }

    // ---- release + ticket: 8th arrival merges this q-tile -----------------
    __syncthreads();                                  // drains vmcnt: stores at L2
    if (tid == 0) {
        __threadfence();                              // L2 writeback (release)
        s_last = atomicAdd(&tick[b * 32 + tau], 1);
    }
    __syncthreads();
    if (s_last != 7) return;                          // block-uniform
    __threadfence();                                  // acquire (invalidate)

    // ---- merge (former combine_kn): wave w merges rows w*16 .. w*16+15 ----
    int items[8];
    #pragma unroll
    for (int s2 = 0; s2 < 8; ++s2) {
        const int x2  = b * 2 + (s2 & 1);
        const int sl2 = (31 - tau) * 4 + (s2 >> 1);
        items[s2] = sl2 * 8 + x2;
    }
    float Mv[8], Lv[8];
    #pragma unroll
    for (int s2 = 0; s2 < 8; ++s2) {
        Mv[s2] = Mp[(size_t)items[s2] * 128 + w * 16 + c];
        Lv[s2] = Lp[(size_t)items[s2] * 128 + w * 16 + c];
    }
    float M2 = Mv[0];
    #pragma unroll
    for (int s2 = 1; s2 < 8; ++s2) M2 = fmaxf(M2, Mv[s2]);
    float L2 = 0.f;
    float a2[8];
    #pragma unroll
    for (int s2 = 0; s2 < 8; ++s2) {
        a2[s2] = exp2f(Mv[s2] - M2);                  // 0 for empty partials
        L2 += Lv[s2] * a2[s2];
    }
    const float inv = 1.f / L2;

    floatx4 acc[4];
    #pragma unroll
    for (int mt = 0; mt < 4; ++mt) acc[mt] = floatx4{0.f, 0.f, 0.f, 0.f};
    #pragma unroll
    for (int s2 = 0; s2 < 8; ++s2) {
        const float* Ob2 = Opart + ((size_t)items[s2] * 8 + w) * 1024;
        #pragma unroll
        for (int mt = 0; mt < 4; ++mt) {
            const floatx4 v = *(const floatx4*)(Ob2 + mt * 256 + lane * 4);
            acc[mt] += v * a2[s2];
        }
    }

    float* sO = (float*)smem + w * 1088;              // per-wave [64][17]
    #pragma unroll
    for (int mt = 0; mt < 4; ++mt)
        #pragma unroll
        for (int r = 0; r < 4; ++r)
            sO[(mt * 16 + q * 4 + r) * 17 + c] = acc[mt][r] * inv;
    __syncthreads();

    const int orow = lane >> 2;                       // 0..15
    const int seg  = lane & 3;                        // h segment of 16
    float* dst = out + (size_t)(b * T_ + tau * 128 + w * 16 + orow) * H_ + seg * 16;
    #pragma unroll
    for (int v4 = 0; v4 < 4; ++v4) {
        float4 vv;
        vv.x = sO[(seg * 16 + v4 * 4 + 0) * 17 + orow];
        vv.y = sO[(seg * 16 + v4 * 4 + 1) * 17 + orow];
        vv.z = sO[(seg * 16 + v4 * 4 + 2) * 17 + orow];
        vv.w = sO[(seg * 16 + v4 * 4 + 3) * 17 + orow];
        *(float4*)(dst + v4 * 4) = vv;
    }
}

extern "C" void kernel_launch(void* const* d_in, const int* in_sizes, int n_in,
                              void* d_out, int out_size, void* d_ws, size_t ws_size,
                              hipStream_t stream) {
    const float* x  = (const float*)d_in[0];
    const float* Wq = (const float*)d_in[1];
    const float* Wk = (const float*)d_in[2];
    const float* Wv = (const float*)d_in[3];
    float* out = (float*)d_out;

    _Float16* ws = (_Float16*)d_ws;
    _Float16* Wt2 = ws;                               //   192*1024 = 196608 halfs
    _Float16* Qh  = ws + 196608;                      // 16384*64  = 1048576
    _Float16* Kpk = Qh + 1048576;                     // [4][64][4096]
    _Float16* Vpk = Kpk + 1048576;                    // [4][64][4096]
    float* Opart = (float*)(ws + 3342336);            // [1024][8][1024] f32 = 32 MB
    float* Mp    = Opart + 8388608;                   // [1024][128]
    float* Lp    = Mp + 131072;                       // [1024][128]
    int*   tick  = (int*)(Lp + 131072);               // [128] merge tickets

    hipLaunchKernelGGL(pack_w_kn, dim3(768), dim3(256), 0, stream,
                       Wq, Wk, Wv, Wt2, tick);
    hipLaunchKernelGGL(qkv_kn, dim3((B_ * T_) / 32), dim3(512), 0, stream,
                       x, Wt2, Qh, Kpk, Vpk);
    hipLaunchKernelGGL(attn_kn, dim3(1024), dim3(512), 0, stream,
                       Qh, Kpk, Vpk, Opart, Mp, Lp, tick, out);
}

// Round 12
// 145.348 us; speedup vs baseline: 1.6237x; 1.6237x over previous
//
#include <hip/hip_runtime.h>

#define B_ 4
#define T_ 4096
#define C_ 1024
#define H_ 64

typedef _Float16 half8  __attribute__((ext_vector_type(8)));
typedef _Float16 half4_ __attribute__((ext_vector_type(4)));
typedef float    floatx4 __attribute__((ext_vector_type(4)));

#define MFMA16(a, b, c)  __builtin_amdgcn_mfma_f32_16x16x32_f16(a, b, c, 0, 0, 0)
#define MFMA16K(a, b, c) __builtin_amdgcn_mfma_f32_16x16x16f16(a, b, c, 0, 0, 0)
#define LO4(v) __builtin_shufflevector(v, v, 0, 1, 2, 3)
#define HI4(v) __builtin_shufflevector(v, v, 4, 5, 6, 7)

// ---------------------------------------------------------------------------
// Kernel 1: pack W into MFMA-fragment order + zero the 128 merge tickets.
// ---------------------------------------------------------------------------
__global__ __launch_bounds__(256) void pack_w_kn(
    const float* __restrict__ Wq, const float* __restrict__ Wk,
    const float* __restrict__ Wv, _Float16* __restrict__ Wt2,
    int* __restrict__ tick)
{
    if (blockIdx.x == 0 && threadIdx.x < 128) tick[threadIdx.x] = 0;
    const int idx  = blockIdx.x * 256 + threadIdx.x;  // 0 .. 196607
    const int mt   = idx >> 14;
    const int j    = (idx >> 10) & 15;
    const int f    = (idx >> 9) & 1;
    const int lane = (idx >> 3) & 63;
    const int jj   = idx & 7;
    const int q = lane >> 4, c = lane & 15;
    const int k  = j * 64 + f * 32 + q * 8 + jj;
    const int hp = mt * 16 + c;                       // 0..191
    const float* W = (hp < 64) ? Wq : (hp < 128) ? Wk : Wv;
    Wt2[idx] = (_Float16)W[k * H_ + (hp & 63)];
}

// ---------------------------------------------------------------------------
// Kernel 2: fused QKV projection (unchanged).  Vpk in 16x16x16 A-frag order.
// ---------------------------------------------------------------------------
__global__ __launch_bounds__(512) void qkv_kn(
    const float* __restrict__ x, const _Float16* __restrict__ Wt2,
    _Float16* __restrict__ Qh, _Float16* __restrict__ Kpk,
    _Float16* __restrict__ Vpk)
{
    __shared__ _Float16 xs[2][32][72];                // 9216 B
    const int tid  = threadIdx.x;
    const int lane = tid & 63, w = tid >> 6;
    const int q    = lane >> 4, c = lane & 15;
    const int nt   = w & 1;                           // n-half (16 rows)
    const int mg   = w >> 1;                          // m-group (3 m-tiles)
    const int row0 = blockIdx.x * 32;

    const int srow = tid >> 4, scol = (tid & 15) * 4;
    const float* xg = x + (size_t)(row0 + srow) * C_ + scol;

    floatx4 acc[3];
    #pragma unroll
    for (int i = 0; i < 3; ++i) acc[i] = floatx4{0.f, 0.f, 0.f, 0.f};

    float4 g = *(const float4*)xg;                    // preload tile 0

    for (int j = 0; j < 16; ++j) {
        half4_ hv;
        hv[0] = (_Float16)g.x; hv[1] = (_Float16)g.y;
        hv[2] = (_Float16)g.z; hv[3] = (_Float16)g.w;
        *(half4_*)(&xs[j & 1][srow][scol]) = hv;
        __syncthreads();
        if (j < 15) g = *(const float4*)(xg + (j + 1) * 64);

        const _Float16* xrow = &xs[j & 1][nt * 16 + c][q * 8];
        const half8 b0 = *(const half8*)xrow;
        const half8 b1 = *(const half8*)(xrow + 32);

        half8 a[6];
        #pragma unroll
        for (int i = 0; i < 3; ++i) {
            const size_t fb = ((size_t)((mg * 3 + i) * 16 + j) * 2) * 512 + lane * 8;
            a[i * 2]     = *(const half8*)(Wt2 + fb);
            a[i * 2 + 1] = *(const half8*)(Wt2 + fb + 512);
        }
        #pragma unroll
        for (int i = 0; i < 3; ++i) {
            acc[i] = MFMA16(a[i * 2],     b0, acc[i]);
            acc[i] = MFMA16(a[i * 2 + 1], b1, acc[i]);
        }
    }

    const int row = row0 + nt * 16 + c;
    const int b = row >> 12, t4 = row & (T_ - 1);
    const int kt = t4 >> 6;
    const size_t tbase = ((size_t)b * 64 + kt) * 4096;
    const int mtk = (t4 >> 4) & 3;
    const int kk  = t4 & 63;

    #pragma unroll
    for (int i = 0; i < 3; ++i) {
        const int gi = mg * 3 + i;
        if (gi < 4) {                                 // Q row-major
            half4_ v;
            #pragma unroll
            for (int r = 0; r < 4; ++r) v[r] = (_Float16)acc[i][r];
            *(half4_*)(Qh + (size_t)row * H_ + gi * 16 + q * 4) = v;
        } else if (gi < 8) {                          // K fragment-packed (16x16x32 A-frag)
            half4_ v;
            #pragma unroll
            for (int r = 0; r < 4; ++r) v[r] = (_Float16)acc[i][r];
            const int e  = gi - 4;
            const int f  = e >> 1;
            const int qa = (e * 2 + (q >> 1)) & 3;
            *(half4_*)(Kpk + tbase + ((size_t)(mtk * 2 + f) * 64 + qa * 16 + c) * 8
                       + (q & 1) * 4) = v;
        } else {                                      // V 16x16x16 A-frag packed
            const int mtv = gi - 8;
            const int qa2 = (kk >> 2) & 3;
            const int h4  = (kk >> 4) & 1;
            const int f2  = kk >> 5;
            const int i2  = kk & 3;
            #pragma unroll
            for (int r = 0; r < 4; ++r) {
                const int cv = q * 4 + r;             // h & 15
                Vpk[tbase + ((size_t)(mtv * 2 + f2) * 64 + qa2 * 16 + cv) * 8
                    + h4 * 4 + i2] = (_Float16)acc[i][r];
            }
        }
    }
}

// ---------------------------------------------------------------------------
// Kernel 3: causal flash attention, LDS-shared K/V, fused split-K merge.
// Round-10 post-mortem: the merge was correct but __threadfence() (device-
// scope release) emits buffer_wbl2 -> per-block full-L2 writeback x 1024 =
// the whole 110 us regression.  Fix: place ALL 8 slices of a q-tile on ONE
// XCD (xcd = 2b + (tau&1), bid&7 round-robin) so merge visibility needs only
// the shared same-XCD L2: producer stores drain at the pre-ticket barrier
// (write-through L1 -> L2), ticket atomicAdd executes at the same TCC, and
// the 8th block's L1-cold reads hit L2.  NO fences.  Balanced slot folding
// (v even: tau'=15-(r>>2); v odd: tau'=r>>2) pairs heavy+light tiles per CU.
// Hang-audit (r11 infra failure): no spin-waits; ticket is single-pass
// (one atomicAdd per block, exactly one block merges); all barriers on
// block-uniform paths; wrong-XCD assumption would fail absmax, not hang.
// ---------------------------------------------------------------------------
__global__ __launch_bounds__(512, 4) void attn_kn(
    const _Float16* __restrict__ Qh, const _Float16* __restrict__ Kpk,
    const _Float16* __restrict__ Vpk, float* __restrict__ Opart,
    float* __restrict__ Mp, float* __restrict__ Lp, int* __restrict__ tick,
    float* __restrict__ out)
{
    __shared__ __align__(16) char smem[36864];        // KVs overlay / merge sO
    __shared__ int s_last;
    _Float16 (*KVs)[2][4096] = (_Float16 (*)[2][4096])smem;
    const int tid  = threadIdx.x;
    const int lane = tid & 63;
    const int w    = tid >> 6;                        // 0..7
    const int q    = lane >> 4, c = lane & 15;

    // decode: all 8 slices of (b,tau) on xcd = 2b + (tau&1); balanced fold
    const int bid  = blockIdx.x;
    const int xcd  = bid & 7;
    const int slot = bid >> 3;                        // 0..127
    const int b    = xcd >> 1;
    const int e    = xcd & 1;                         // tau parity
    const int v    = slot >> 5;                       // 0..3
    const int r    = slot & 31;                       // 0..31
    const int tp   = (v & 1) ? (r >> 2) : (15 - (r >> 2));  // tau' 0..15
    const int s    = ((v >> 1) << 2) | (r & 3);       // split-K slice 0..7
    const int tau  = tp * 2 + e;                      // 0..31
    const int row0 = tau * 128;
    const int wrow0 = row0 + w * 16;                  // this wave's first row
    const int nk_blk = 2 * tau + 2;                   // block stages kt<nk_blk
    const int nk_w   = (wrow0 >> 6) + 1;              // wave needs kt<nk_w
    const int ntb = (s < nk_blk) ? (((nk_blk - 1 - s) >> 3) + 1) : 0;

    // Q B-frag for this wave's 16 rows, pre-scaled by (1/8)*log2(e)
    const _Float16* qb = Qh + (size_t)(b * T_ + wrow0 + c) * H_;
    half8 bq0 = *(const half8*)(qb + q * 8);
    half8 bq1 = *(const half8*)(qb + 32 + q * 8);
    const _Float16 qs = (_Float16)0.18033688f;
    bq0 *= qs; bq1 *= qs;

    floatx4 o[4];
    #pragma unroll
    for (int i = 0; i < 4; ++i) o[i] = floatx4{0.f, 0.f, 0.f, 0.f};
    float m = -3.0e38f, l = 0.f;

    const _Float16* Kb = Kpk + (size_t)b * 262144;    // b * 64 * 4096
    const _Float16* Vb = Vpk + (size_t)b * 262144;

    if (ntb > 0) {                                    // stage first tile
        const _Float16* Kt = Kb + (size_t)s * 4096;
        const _Float16* Vt = Vb + (size_t)s * 4096;
        *(half8*)(&KVs[0][0][tid * 8]) = *(const half8*)(Kt + tid * 8);
        *(half8*)(&KVs[0][1][tid * 8]) = *(const half8*)(Vt + tid * 8);
    }
    __syncthreads();

    #pragma unroll 1
    for (int i = 0; i < ntb; ++i) {
        const int kt = s + 8 * i;
        const bool more = (i + 1 < ntb);
        half8 gk, gv;
        if (more) {                                   // issue next-tile loads
            const _Float16* Kt = Kb + (size_t)(kt + 8) * 4096;
            const _Float16* Vt = Vb + (size_t)(kt + 8) * 4096;
            gk = *(const half8*)(Kt + tid * 8);
            gv = *(const half8*)(Vt + tid * 8);
        }

        if (kt < nk_w) {                              // wave-uniform guard
            const _Float16* Ks = &KVs[i & 1][0][0];
            const _Float16* Vs = &KVs[i & 1][1][0];

            floatx4 sS[4];
            __builtin_amdgcn_s_setprio(1);
            #pragma unroll
            for (int mt = 0; mt < 4; ++mt) {
                const half8 ka = *(const half8*)(Ks + ((mt * 2)     * 64 + lane) * 8);
                const half8 kb2= *(const half8*)(Ks + ((mt * 2 + 1) * 64 + lane) * 8);
                floatx4 z = floatx4{0.f, 0.f, 0.f, 0.f};
                z = MFMA16(ka, bq0, z);
                sS[mt] = MFMA16(kb2, bq1, z);
            }
            __builtin_amdgcn_s_setprio(0);

            if (kt == nk_w - 1) {                     // causal mask (diag tile)
                const int kb0 = kt * 64;
                #pragma unroll
                for (int mt = 0; mt < 4; ++mt)
                    #pragma unroll
                    for (int r2 = 0; r2 < 4; ++r2)
                        if (kb0 + mt * 16 + q * 4 + r2 > wrow0 + c)
                            sS[mt][r2] = -3.0e38f;
            }

            // online softmax (lane holds 16 scores of ONE q-row); T13 defer
            float mx = sS[0][0];
            #pragma unroll
            for (int mt = 0; mt < 4; ++mt)
                #pragma unroll
                for (int r2 = 0; r2 < 4; ++r2) mx = fmaxf(mx, sS[mt][r2]);
            mx = fmaxf(mx, __shfl_xor(mx, 16, 64));
            mx = fmaxf(mx, __shfl_xor(mx, 32, 64));
            if (!__all(mx <= m + 8.f)) {
                const float mn    = fmaxf(m, mx);
                const float alpha = exp2f(m - mn);
                l *= alpha;
                #pragma unroll
                for (int mt = 0; mt < 4; ++mt) o[mt] *= alpha;
                m = mn;
            }
            half4_ ph[4];
            float sl = 0.f;
            #pragma unroll
            for (int mt = 0; mt < 4; ++mt)
                #pragma unroll
                for (int r2 = 0; r2 < 4; ++r2) {
                    const float ev = exp2f(sS[mt][r2] - m);
                    sl += ev;
                    ph[mt][r2] = (_Float16)ev;
                }
            sl += __shfl_xor(sl, 16, 64);
            sl += __shfl_xor(sl, 32, 64);
            l += sl;

            __builtin_amdgcn_s_setprio(1);
            #pragma unroll
            for (int mt = 0; mt < 4; ++mt) {
                const half8 va = *(const half8*)(Vs + ((mt * 2)     * 64 + lane) * 8);
                const half8 vb = *(const half8*)(Vs + ((mt * 2 + 1) * 64 + lane) * 8);
                o[mt] = MFMA16K(LO4(va), ph[0], o[mt]);
                o[mt] = MFMA16K(HI4(va), ph[1], o[mt]);
                o[mt] = MFMA16K(LO4(vb), ph[2], o[mt]);
                o[mt] = MFMA16K(HI4(vb), ph[3], o[mt]);
            }
            __builtin_amdgcn_s_setprio(0);
        }

        __syncthreads();                              // all reads of buf done
        if (more) {                                   // block-uniform
            *(half8*)(&KVs[(i + 1) & 1][0][tid * 8]) = gk;
            *(half8*)(&KVs[(i + 1) & 1][1][tid * 8]) = gv;
            __syncthreads();
        }
    }

    // ---- write per-wave unnormalized partial (fragment-native, coalesced) -
    float* Ob = Opart + ((size_t)bid * 8 + w) * 1024;
    #pragma unroll
    for (int mt = 0; mt < 4; ++mt)
        *(floatx4*)(Ob + mt * 256 + lane * 4) = o[mt];
    if (q == 0) {
        Mp[(size_t)bid * 128 + w * 16 + c] = m;
        Lp[(size_t)bid * 128 + w * 16 + c] = l;
    }

    // ---- ticket (same-XCD L2 visibility; no fences): 8th arrival merges ---
    __syncthreads();                                  // drains vmcnt: stores in L2
    if (tid == 0) s_last = atomicAdd(&tick[b * 32 + tau], 1);
    __syncthreads();
    if (s_last != 7) return;                          // block-uniform
    asm volatile("" ::: "memory");                    // compiler-only ordering

    // ---- merge: wave w merges q-rows w*16 .. w*16+15 of tile (b, tau) -----
    const int tp2 = tau >> 1;
    int items[8];
    #pragma unroll
    for (int s2 = 0; s2 < 8; ++s2) {
        const int v2 = ((s2 >> 2) << 1) | ((tp2 >= 8) ? 0 : 1);
        const int r2 = ((v2 & 1) ? (tp2 << 2) : ((15 - tp2) << 2)) | (s2 & 3);
        items[s2] = (v2 * 32 + r2) * 8 + xcd;
    }
    float Mv[8], Lv[8];
    #pragma unroll
    for (int s2 = 0; s2 < 8; ++s2) {
        Mv[s2] = Mp[(size_t)items[s2] * 128 + w * 16 + c];
        Lv[s2] = Lp[(size_t)items[s2] * 128 + w * 16 + c];
    }
    float M2 = Mv[0];
    #pragma unroll
    for (int s2 = 1; s2 < 8; ++s2) M2 = fmaxf(M2, Mv[s2]);
    float L2 = 0.f;
    float a2[8];
    #pragma unroll
    for (int s2 = 0; s2 < 8; ++s2) {
        a2[s2] = exp2f(Mv[s2] - M2);                  // 0 for empty partials
        L2 += Lv[s2] * a2[s2];
    }
    const float inv = 1.f / L2;

    floatx4 acc[4];
    #pragma unroll
    for (int mt = 0; mt < 4; ++mt) acc[mt] = floatx4{0.f, 0.f, 0.f, 0.f};
    #pragma unroll
    for (int s2 = 0; s2 < 8; ++s2) {
        const float* Ob2 = Opart + ((size_t)items[s2] * 8 + w) * 1024;
        #pragma unroll
        for (int mt = 0; mt < 4; ++mt) {
            const floatx4 vv = *(const floatx4*)(Ob2 + mt * 256 + lane * 4);
            acc[mt] += vv * a2[s2];
        }
    }

    float* sO = (float*)smem + w * 1088;              // per-wave [64][17]
    #pragma unroll
    for (int mt = 0; mt < 4; ++mt)
        #pragma unroll
        for (int r2 = 0; r2 < 4; ++r2)
            sO[(mt * 16 + q * 4 + r2) * 17 + c] = acc[mt][r2] * inv;
    __syncthreads();

    const int orow = lane >> 2;                       // 0..15
    const int seg  = lane & 3;                        // h segment of 16
    float* dst = out + (size_t)(b * T_ + tau * 128 + w * 16 + orow) * H_ + seg * 16;
    #pragma unroll
    for (int v4 = 0; v4 < 4; ++v4) {
        float4 vv;
        vv.x = sO[(seg * 16 + v4 * 4 + 0) * 17 + orow];
        vv.y = sO[(seg * 16 + v4 * 4 + 1) * 17 + orow];
        vv.z = sO[(seg * 16 + v4 * 4 + 2) * 17 + orow];
        vv.w = sO[(seg * 16 + v4 * 4 + 3) * 17 + orow];
        *(float4*)(dst + v4 * 4) = vv;
    }
}

extern "C" void kernel_launch(void* const* d_in, const int* in_sizes, int n_in,
                              void* d_out, int out_size, void* d_ws, size_t ws_size,
                              hipStream_t stream) {
    const float* x  = (const float*)d_in[0];
    const float* Wq = (const float*)d_in[1];
    const float* Wk = (const float*)d_in[2];
    const float* Wv = (const float*)d_in[3];
    float* out = (float*)d_out;

    _Float16* ws = (_Float16*)d_ws;
    _Float16* Wt2 = ws;                               //   192*1024 = 196608 halfs
    _Float16* Qh  = ws + 196608;                      // 16384*64  = 1048576
    _Float16* Kpk = Qh + 1048576;                     // [4][64][4096]
    _Float16* Vpk = Kpk + 1048576;                    // [4][64][4096]
    float* Opart = (float*)(ws + 3342336);            // [1024][8][1024] f32 = 32 MB
    float* Mp    = Opart + 8388608;                   // [1024][128]
    float* Lp    = Mp + 131072;                       // [1024][128]
    int*   tick  = (int*)(Lp + 131072);               // [128] merge tickets

    hipLaunchKernelGGL(pack_w_kn, dim3(768), dim3(256), 0, stream,
                       Wq, Wk, Wv, Wt2, tick);
    hipLaunchKernelGGL(qkv_kn, dim3((B_ * T_) / 32), dim3(512), 0, stream,
                       x, Wt2, Qh, Kpk, Vpk);
    hipLaunchKernelGGL(attn_kn, dim3(1024), dim3(512), 0, stream,
                       Qh, Kpk, Vpk, Opart, Mp, Lp, tick, out);
}

// Round 13
// 136.877 us; speedup vs baseline: 1.7242x; 1.0619x over previous
//
#include <hip/hip_runtime.h>

#define B_ 4
#define T_ 4096
#define C_ 1024
#define H_ 64

typedef _Float16 half8  __attribute__((ext_vector_type(8)));
typedef _Float16 half4_ __attribute__((ext_vector_type(4)));
typedef float    floatx4 __attribute__((ext_vector_type(4)));

#define MFMA16(a, b, c)  __builtin_amdgcn_mfma_f32_16x16x32_f16(a, b, c, 0, 0, 0)
#define MFMA16K(a, b, c) __builtin_amdgcn_mfma_f32_16x16x16f16(a, b, c, 0, 0, 0)
#define LO4(v) __builtin_shufflevector(v, v, 0, 1, 2, 3)
#define HI4(v) __builtin_shufflevector(v, v, 4, 5, 6, 7)

// ---------------------------------------------------------------------------
// Kernel 1: pack W into MFMA-fragment order.  Grid reduced 768 -> 96 blocks
// (8 elems/thread, one half8 store): same 1.1 MB of traffic, 8x less
// launch/ramp overhead (this kernel was launch-dominated at ~5 us).
// ---------------------------------------------------------------------------
__global__ __launch_bounds__(256) void pack_w_kn(
    const float* __restrict__ Wq, const float* __restrict__ Wk,
    const float* __restrict__ Wv, _Float16* __restrict__ Wt2)
{
    const int base = (blockIdx.x * 256 + threadIdx.x) * 8;  // 0..196600, step 8
    const int mt   = base >> 14;
    const int j    = (base >> 10) & 15;
    const int f    = (base >> 9) & 1;
    const int lane = (base >> 3) & 63;
    const int q = lane >> 4, c = lane & 15;
    const int k0 = j * 64 + f * 32 + q * 8;
    const int hp = mt * 16 + c;                       // 0..191
    const float* W = (hp < 64) ? Wq : (hp < 128) ? Wk : Wv;
    const float* src = W + k0 * H_ + (hp & 63);
    half8 v;
    #pragma unroll
    for (int jj = 0; jj < 8; ++jj) v[jj] = (_Float16)src[jj * H_];
    *(half8*)(Wt2 + base) = v;
}

// ---------------------------------------------------------------------------
// Kernel 2: fused QKV projection (unchanged).  Vpk in 16x16x16 A-frag order.
// At its memory roofline: 92 MB @ 6.3 TB/s = 14.6 us.
// ---------------------------------------------------------------------------
__global__ __launch_bounds__(512) void qkv_kn(
    const float* __restrict__ x, const _Float16* __restrict__ Wt2,
    _Float16* __restrict__ Qh, _Float16* __restrict__ Kpk,
    _Float16* __restrict__ Vpk)
{
    __shared__ _Float16 xs[2][32][72];                // 9216 B
    const int tid  = threadIdx.x;
    const int lane = tid & 63, w = tid >> 6;
    const int q    = lane >> 4, c = lane & 15;
    const int nt   = w & 1;                           // n-half (16 rows)
    const int mg   = w >> 1;                          // m-group (3 m-tiles)
    const int row0 = blockIdx.x * 32;

    const int srow = tid >> 4, scol = (tid & 15) * 4;
    const float* xg = x + (size_t)(row0 + srow) * C_ + scol;

    floatx4 acc[3];
    #pragma unroll
    for (int i = 0; i < 3; ++i) acc[i] = floatx4{0.f, 0.f, 0.f, 0.f};

    float4 g = *(const float4*)xg;                    // preload tile 0

    for (int j = 0; j < 16; ++j) {
        half4_ hv;
        hv[0] = (_Float16)g.x; hv[1] = (_Float16)g.y;
        hv[2] = (_Float16)g.z; hv[3] = (_Float16)g.w;
        *(half4_*)(&xs[j & 1][srow][scol]) = hv;
        __syncthreads();
        if (j < 15) g = *(const float4*)(xg + (j + 1) * 64);

        const _Float16* xrow = &xs[j & 1][nt * 16 + c][q * 8];
        const half8 b0 = *(const half8*)xrow;
        const half8 b1 = *(const half8*)(xrow + 32);

        half8 a[6];
        #pragma unroll
        for (int i = 0; i < 3; ++i) {
            const size_t fb = ((size_t)((mg * 3 + i) * 16 + j) * 2) * 512 + lane * 8;
            a[i * 2]     = *(const half8*)(Wt2 + fb);
            a[i * 2 + 1] = *(const half8*)(Wt2 + fb + 512);
        }
        #pragma unroll
        for (int i = 0; i < 3; ++i) {
            acc[i] = MFMA16(a[i * 2],     b0, acc[i]);
            acc[i] = MFMA16(a[i * 2 + 1], b1, acc[i]);
        }
    }

    const int row = row0 + nt * 16 + c;
    const int b = row >> 12, t4 = row & (T_ - 1);
    const int kt = t4 >> 6;
    const size_t tbase = ((size_t)b * 64 + kt) * 4096;
    const int mtk = (t4 >> 4) & 3;
    const int kk  = t4 & 63;

    #pragma unroll
    for (int i = 0; i < 3; ++i) {
        const int gi = mg * 3 + i;
        if (gi < 4) {                                 // Q row-major
            half4_ v;
            #pragma unroll
            for (int r = 0; r < 4; ++r) v[r] = (_Float16)acc[i][r];
            *(half4_*)(Qh + (size_t)row * H_ + gi * 16 + q * 4) = v;
        } else if (gi < 8) {                          // K fragment-packed (16x16x32 A-frag)
            half4_ v;
            #pragma unroll
            for (int r = 0; r < 4; ++r) v[r] = (_Float16)acc[i][r];
            const int e  = gi - 4;
            const int f  = e >> 1;
            const int qa = (e * 2 + (q >> 1)) & 3;
            *(half4_*)(Kpk + tbase + ((size_t)(mtk * 2 + f) * 64 + qa * 16 + c) * 8
                       + (q & 1) * 4) = v;
        } else {                                      // V 16x16x16 A-frag packed
            const int mtv = gi - 8;
            const int qa2 = (kk >> 2) & 3;
            const int h4  = (kk >> 4) & 1;
            const int f2  = kk >> 5;
            const int i2  = kk & 3;
            #pragma unroll
            for (int r = 0; r < 4; ++r) {
                const int cv = q * 4 + r;             // h & 15
                Vpk[tbase + ((size_t)(mtv * 2 + f2) * 64 + qa2 * 16 + cv) * 8
                    + h4 * 4 + i2] = (_Float16)acc[i][r];
            }
        }
    }
}

// ---------------------------------------------------------------------------
// Kernel 3: causal flash attention — round-8 structure verbatim (best
// measured: direct out, no partials; r9-r12 showed every split-K partial
// scheme costs more than its traffic cut saves).  One trim: the last-iter
// K-prefetch is now GUARDED (wave-uniform branch) instead of clamped —
// r8 re-loaded the same 8 KB tile uselessly on every wave's final
// iteration = ~67 MB (12%) of pointless L2 traffic.
// ---------------------------------------------------------------------------
__global__ __launch_bounds__(512, 4) void attn_kn(
    const _Float16* __restrict__ Qh, const _Float16* __restrict__ Kpk,
    const _Float16* __restrict__ Vpk, float* __restrict__ out)
{
    __shared__ __align__(16) char smem[36864];
    const int lane = threadIdx.x & 63;
    const int w    = threadIdx.x >> 6;                // 0..7
    const int q    = lane >> 4, c = lane & 15;

    // XCD-aware decode: batch per XCD pair, heavy tiles first
    const int bid  = blockIdx.x;
    const int xcd  = bid & 7;
    const int slot = bid >> 3;                        // 0..127
    const int b    = xcd >> 1;
    const int t    = 255 - ((slot << 1) | (xcd & 1));
    const int row0 = t * 16;
    const int grow = b * T_ + row0;
    const int nk   = (t >> 2) + 1;                    // 64-key tiles (last=diag)

    // Q B-frag, pre-scaled by (1/8)*log2(e)
    half8 bq0 = *(const half8*)(Qh + (size_t)(grow + c) * H_ + q * 8);
    half8 bq1 = *(const half8*)(Qh + (size_t)(grow + c) * H_ + 32 + q * 8);
    const _Float16 qs = (_Float16)0.18033688f;
    bq0 *= qs; bq1 *= qs;

    floatx4 o[4];
    #pragma unroll
    for (int i = 0; i < 4; ++i) o[i] = floatx4{0.f, 0.f, 0.f, 0.f};
    float m = -3.0e38f, l = 0.f;

    const _Float16* Kb = Kpk + (size_t)b * 262144;    // b * 64 * 4096
    const _Float16* Vb = Vpk + (size_t)b * 262144;

    half8 k0[4], k1[4], v0[4], v1[4];
    {   // preload K for this wave's first tile (kt = w; always in-bounds)
        const _Float16* Kt = Kb + (size_t)w * 4096;
        #pragma unroll
        for (int mt = 0; mt < 4; ++mt) {
            k0[mt] = *(const half8*)(Kt + ((mt * 2)     * 64 + lane) * 8);
            k1[mt] = *(const half8*)(Kt + ((mt * 2 + 1) * 64 + lane) * 8);
        }
    }

    #pragma unroll 1
    for (int kt = w; kt < nk; kt += 8) {
        const int kb = kt * 64;

        // QK^T: 64 keys x 16 q
        floatx4 s[4];
        __builtin_amdgcn_s_setprio(1);
        #pragma unroll
        for (int mt = 0; mt < 4; ++mt) {
            floatx4 z = floatx4{0.f, 0.f, 0.f, 0.f};
            z = MFMA16(k0[mt], bq0, z);
            s[mt] = MFMA16(k1[mt], bq1, z);
        }
        __builtin_amdgcn_s_setprio(0);

        // V(kt): latency hides under softmax
        const _Float16* Vt = Vb + (size_t)kt * 4096;
        #pragma unroll
        for (int mt = 0; mt < 4; ++mt) {
            v0[mt] = *(const half8*)(Vt + ((mt * 2)     * 64 + lane) * 8);
            v1[mt] = *(const half8*)(Vt + ((mt * 2 + 1) * 64 + lane) * 8);
        }
        // K(kt+8) prefetch into the just-freed K regs (guarded, wave-uniform)
        if (kt + 8 < nk) {
            const _Float16* Kt = Kb + (size_t)(kt + 8) * 4096;
            #pragma unroll
            for (int mt = 0; mt < 4; ++mt) {
                k0[mt] = *(const half8*)(Kt + ((mt * 2)     * 64 + lane) * 8);
                k1[mt] = *(const half8*)(Kt + ((mt * 2 + 1) * 64 + lane) * 8);
            }
        }

        if (kt == nk - 1) {                           // causal mask (diag tile)
            #pragma unroll
            for (int mt = 0; mt < 4; ++mt)
                #pragma unroll
                for (int r = 0; r < 4; ++r)
                    if (kb + mt * 16 + q * 4 + r > row0 + c) s[mt][r] = -3.0e38f;
        }

        // online softmax, lane holds 16 scores of ONE q-row; defer-rescale
        float mx = s[0][0];
        #pragma unroll
        for (int mt = 0; mt < 4; ++mt)
            #pragma unroll
            for (int r = 0; r < 4; ++r) mx = fmaxf(mx, s[mt][r]);
        mx = fmaxf(mx, __shfl_xor(mx, 16, 64));
        mx = fmaxf(mx, __shfl_xor(mx, 32, 64));
        if (!__all(mx <= m + 8.f)) {                  // T13: rescale only on growth
            const float mn    = fmaxf(m, mx);
            const float alpha = exp2f(m - mn);
            l *= alpha;
            #pragma unroll
            for (int mt = 0; mt < 4; ++mt) o[mt] *= alpha;
            m = mn;
        }
        half4_ ph[4];
        float sl = 0.f;
        #pragma unroll
        for (int mt = 0; mt < 4; ++mt)
            #pragma unroll
            for (int r = 0; r < 4; ++r) {
                const float ev = exp2f(s[mt][r] - m);
                sl += ev;
                ph[mt][r] = (_Float16)ev;
            }
        sl += __shfl_xor(sl, 16, 64);
        sl += __shfl_xor(sl, 32, 64);
        l += sl;

        // O^T += V^T · P^T (P stays in registers as 16x16x16 B-frags)
        __builtin_amdgcn_s_setprio(1);
        #pragma unroll
        for (int mt = 0; mt < 4; ++mt) {
            o[mt] = MFMA16K(LO4(v0[mt]), ph[0], o[mt]);
            o[mt] = MFMA16K(HI4(v0[mt]), ph[1], o[mt]);
            o[mt] = MFMA16K(LO4(v1[mt]), ph[2], o[mt]);
            o[mt] = MFMA16K(HI4(v1[mt]), ph[3], o[mt]);
        }
        __builtin_amdgcn_s_setprio(0);
    }

    // ---- flash combine across the 8 waves (direct out write) -------------
    float* Ol = (float*)smem;                         // [8][1088] (pad 17)
    float* Ml = (float*)(smem + 34816);               // [8][16]
    float* Ll = (float*)(smem + 35328);               // [8][16]
    if (q == 0) Ml[w * 16 + c] = m;
    __syncthreads();
    float M = Ml[c];
    #pragma unroll
    for (int w2 = 1; w2 < 8; ++w2) M = fmaxf(M, Ml[w2 * 16 + c]);
    const float alpha = exp2f(m - M);                 // 0 for empty waves
    if (q == 0) Ll[w * 16 + c] = l * alpha;
    #pragma unroll
    for (int mt = 0; mt < 4; ++mt)
        #pragma unroll
        for (int r = 0; r < 4; ++r)
            Ol[w * 1088 + (mt * 16 + q * 4 + r) * 17 + c] = o[mt][r] * alpha;
    __syncthreads();

    float L = 0.f;
    #pragma unroll
    for (int w2 = 0; w2 < 8; ++w2) L += Ll[w2 * 16 + c];
    const float inv = 1.f / L;
    const int h0 = w * 8 + q * 2;
    float ox = 0.f, oy = 0.f;
    #pragma unroll
    for (int w2 = 0; w2 < 8; ++w2) {
        ox += Ol[w2 * 1088 + h0 * 17 + c];
        oy += Ol[w2 * 1088 + (h0 + 1) * 17 + c];
    }
    float2 st; st.x = ox * inv; st.y = oy * inv;
    *(float2*)(out + (size_t)(grow + c) * H_ + h0) = st;
}

extern "C" void kernel_launch(void* const* d_in, const int* in_sizes, int n_in,
                              void* d_out, int out_size, void* d_ws, size_t ws_size,
                              hipStream_t stream) {
    const float* x  = (const float*)d_in[0];
    const float* Wq = (const float*)d_in[1];
    const float* Wk = (const float*)d_in[2];
    const float* Wv = (const float*)d_in[3];
    float* out = (float*)d_out;

    _Float16* ws = (_Float16*)d_ws;
    _Float16* Wt2 = ws;                               //   192*1024 = 196608
    _Float16* Qh  = ws + 196608;                      // 16384*64  = 1048576
    _Float16* Kpk = Qh + 1048576;                     // [4][64][4096]
    _Float16* Vpk = Kpk + 1048576;                    // [4][64][4096]

    hipLaunchKernelGGL(pack_w_kn, dim3(96), dim3(256), 0, stream, Wq, Wk, Wv, Wt2);
    hipLaunchKernelGGL(qkv_kn, dim3((B_ * T_) / 32), dim3(512), 0, stream,
                       x, Wt2, Qh, Kpk, Vpk);
    hipLaunchKernelGGL(attn_kn, dim3(1024), dim3(512), 0, stream,
                       Qh, Kpk, Vpk, out);
}